// Round 1
// baseline (232.046 us; speedup 1.0000x reference)
//
#include <hip/hip_runtime.h>

typedef unsigned short u16;
typedef __attribute__((ext_vector_type(8))) short short8;
typedef __attribute__((ext_vector_type(4))) float floatx4;

__device__ __forceinline__ u16 f2bf(float x){
  union { float f; unsigned u; } v; v.f = x;
  unsigned r = v.u + 0x7fffu + ((v.u >> 16) & 1u);
  return (u16)(r >> 16);
}

__device__ __forceinline__ void gld16(const u16* g, u16* l){
  __builtin_amdgcn_global_load_lds(
      (const __attribute__((address_space(1))) void*)g,
      (__attribute__((address_space(3))) void*)l, 16, 0, 0);
}

// ---------------- fp32 -> bf16 convert ----------------
__global__ void k_cvt(const float* __restrict__ s, u16* __restrict__ d, int n4){
  int i = blockIdx.x * blockDim.x + threadIdx.x;
  if (i >= n4) return;
  const float4 f = ((const float4*)s)[i];
  unsigned lo = (unsigned)f2bf(f.x) | ((unsigned)f2bf(f.y) << 16);
  unsigned hi = (unsigned)f2bf(f.z) | ((unsigned)f2bf(f.w) << 16);
  ((uint2*)d)[i] = make_uint2(lo, hi);
}

// ---------------- GEMM: C[4096][1024] = A[4096][1024] * W[1024][1024]^T + b --------
// mode 0: Q (bf16 out, [bh][s][64], *qscale)   mode 1: K (bf16, [bh][s][64])
// mode 2: V (bf16, [bh][64][s])                mode 3: fp32 out [4096][1024]
__global__ __launch_bounds__(256) void k_gemm(
    const u16* __restrict__ A,
    const u16* __restrict__ Wq, const u16* __restrict__ Wk, const u16* __restrict__ Wv,
    const float* __restrict__ bq, const float* __restrict__ bk, const float* __restrict__ bv,
    u16* __restrict__ Qo, u16* __restrict__ Ko, u16* __restrict__ Vo,
    float* __restrict__ Fo, int oproj)
{
  const int mode = oproj ? 3 : (int)blockIdx.z;
  const u16* W      = (mode==1) ? Wk : (mode==2) ? Wv : Wq;
  const float* bias = (mode==1) ? bk : (mode==2) ? bv : bq;

  __shared__ u16 lA[2][4096];   // [128 rows][32 k] bf16, k-groups-of-8 swizzled
  __shared__ u16 lB[2][4096];

  const int tid  = threadIdx.x;
  const int row0 = blockIdx.y * 128;
  const int col0 = blockIdx.x * 128;

  // staging: thread covers physical LDS bytes [tid*16, tid*16+16)
  const int srow = tid >> 2;                    // 0..63
  const int sgp  = tid & 3;
  const int sgl  = sgp ^ ((srow >> 1) & 3);     // logical k-group (same for row and row+64)
  const u16* ga0 = A + (row0 + srow)      * 1024 + sgl * 8;
  const u16* ga1 = A + (row0 + srow + 64) * 1024 + sgl * 8;
  const u16* gb0 = W + (col0 + srow)      * 1024 + sgl * 8;
  const u16* gb1 = W + (col0 + srow + 64) * 1024 + sgl * 8;

  // fragment read offsets (ushort units)
  const int l  = tid & 63, w = tid >> 6;
  const int wr = w >> 1,  wc = w & 1;
  const int lr = l & 15,  grp = l >> 4;
  const int sw = (lr >> 1) & 3;
  int aoff[4], boff[4];
#pragma unroll
  for (int m = 0; m < 4; ++m) aoff[m] = (wr*64 + m*16 + lr)*32 + ((grp ^ sw) * 8);
#pragma unroll
  for (int n = 0; n < 4; ++n) boff[n] = (wc*64 + n*16 + lr)*32 + ((grp ^ sw) * 8);

  floatx4 acc[4][4];
#pragma unroll
  for (int m = 0; m < 4; ++m)
#pragma unroll
    for (int n = 0; n < 4; ++n) acc[m][n] = (floatx4){0.f, 0.f, 0.f, 0.f};

#define STAGE(buf, kt_) do { \
    const int k0_ = (kt_) * 32; \
    gld16(ga0 + k0_, &lA[(buf)][tid*8]); \
    gld16(ga1 + k0_, &lA[(buf)][2048 + tid*8]); \
    gld16(gb0 + k0_, &lB[(buf)][tid*8]); \
    gld16(gb1 + k0_, &lB[(buf)][2048 + tid*8]); \
  } while (0)

  STAGE(0, 0);
  __syncthreads();
  for (int kt = 0; kt < 32; ++kt) {
    const int cur = kt & 1;
    if (kt < 31) STAGE(cur ^ 1, kt + 1);
    short8 af[4], bf[4];
#pragma unroll
    for (int m = 0; m < 4; ++m) af[m] = *(const short8*)&lA[cur][aoff[m]];
#pragma unroll
    for (int n = 0; n < 4; ++n) bf[n] = *(const short8*)&lB[cur][boff[n]];
#pragma unroll
    for (int m = 0; m < 4; ++m)
#pragma unroll
      for (int n = 0; n < 4; ++n)
        acc[m][n] = __builtin_amdgcn_mfma_f32_16x16x32_bf16(af[m], bf[n], acc[m][n], 0, 0, 0);
    __syncthreads();
  }
#undef STAGE

  if (mode == 3) {
#pragma unroll
    for (int n = 0; n < 4; ++n) {
      const int cg = col0 + wc*64 + n*16 + lr;
      const float bb = bias[cg];
#pragma unroll
      for (int m = 0; m < 4; ++m) {
        const int rg = row0 + wr*64 + m*16 + grp*4;
#pragma unroll
        for (int j = 0; j < 4; ++j)
          Fo[(rg + j) * 1024 + cg] = acc[m][n][j] + bb;
      }
    }
  } else {
    const float sc = (mode == 0) ? 0.18033688011112042f : 1.0f;  // 0.125*log2(e) for Q
    u16* dst = (mode == 0) ? Qo : (mode == 1) ? Ko : Vo;
#pragma unroll
    for (int n = 0; n < 4; ++n) {
      const int cg = col0 + wc*64 + n*16 + lr;
      const float bb = bias[cg];
      const int h = cg >> 6, d = cg & 63;
#pragma unroll
      for (int m = 0; m < 4; ++m) {
#pragma unroll
        for (int j = 0; j < 4; ++j) {
          const int rg = row0 + wr*64 + m*16 + grp*4 + j;
          const int b = rg >> 11, s5 = rg & 2047;
          const float val = (acc[m][n][j] + bb) * sc;
          int idx;
          if (mode == 2) idx = ((b*16 + h)*64 + d)*2048 + s5;
          else           idx = ((b*16 + h)*2048 + s5)*64 + d;
          dst[idx] = f2bf(val);
        }
      }
    }
  }
}

// ---------------- flash attention ----------------
// grid: x = qtile (16, 128 rows each), y = bh (32). 256 threads, 4 waves x 32 q-rows.
__global__ __launch_bounds__(256) void k_attn(
    const u16* __restrict__ Q, const u16* __restrict__ K,
    const u16* __restrict__ V, u16* __restrict__ O)
{
  __shared__ u16 lK[2][4096];     // [64 keys][64 dk] swizzled groups-of-8
  __shared__ u16 lV[2][4096];     // [64 dk][64 keys] (V^T) swizzled
  __shared__ u16 lP[4][32 * 72];  // per-wave P, padded stride 72

  const int tid = threadIdx.x;
  const int qt = blockIdx.x, bh = blockIdx.y;
  const int l = tid & 63, w = tid >> 6;
  const int lr = l & 15, grp = l >> 4;
  const int q0 = qt * 128;

  const u16* Qh = Q + (size_t)bh * 2048 * 64;
  const u16* Kh = K + (size_t)bh * 2048 * 64;
  const u16* Vh = V + (size_t)bh * 64 * 2048;

  // Q fragments in registers (pre-scaled by 0.125*log2e at projection)
  short8 qf[2][2];
#pragma unroll
  for (int m = 0; m < 2; ++m)
#pragma unroll
    for (int kk = 0; kk < 2; ++kk)
      qf[m][kk] = *(const short8*)(Qh + (q0 + w*32 + m*16 + lr)*64 + kk*32 + grp*8);

  floatx4 accO[2][4];
  float mrow[2][4], lrow[2][4];
#pragma unroll
  for (int m = 0; m < 2; ++m) {
#pragma unroll
    for (int dn = 0; dn < 4; ++dn) accO[m][dn] = (floatx4){0.f, 0.f, 0.f, 0.f};
#pragma unroll
    for (int j = 0; j < 4; ++j) { mrow[m][j] = -1e30f; lrow[m][j] = 0.f; }
  }

  const int srow = tid >> 3, sgp = tid & 7;      // staging: 32 rows/issue, 8 grp of 8
  const int sgl = sgp ^ (srow & 7);
  const int nkt = 2*qt + 2;

#define STAGEKV(buf, kt_) do { \
    gld16(Kh + ((kt_)*64 + srow     )*64 + sgl*8, &lK[(buf)][tid*8]); \
    gld16(Kh + ((kt_)*64 + srow + 32)*64 + sgl*8, &lK[(buf)][2048 + tid*8]); \
    gld16(Vh + (srow     )*2048 + (kt_)*64 + sgl*8, &lV[(buf)][tid*8]); \
    gld16(Vh + (srow + 32)*2048 + (kt_)*64 + sgl*8, &lV[(buf)][2048 + tid*8]); \
  } while (0)

  STAGEKV(0, 0);
  __syncthreads();

  for (int kt = 0; kt < nkt; ++kt) {
    const int cur = kt & 1;
    if (kt + 1 < nkt) STAGEKV(cur ^ 1, kt + 1);

    // S = Q K^T  (in log2 units already)
    floatx4 s[2][4];
#pragma unroll
    for (int m = 0; m < 2; ++m)
#pragma unroll
      for (int n = 0; n < 4; ++n) s[m][n] = (floatx4){0.f, 0.f, 0.f, 0.f};
#pragma unroll
    for (int n = 0; n < 4; ++n) {
      const int key = n*16 + lr;
#pragma unroll
      for (int kk = 0; kk < 2; ++kk) {
        const int gp = (kk*4 + grp) ^ (key & 7);
        short8 kf = *(const short8*)&lK[cur][key*64 + gp*8];
        s[0][n] = __builtin_amdgcn_mfma_f32_16x16x32_bf16(qf[0][kk], kf, s[0][n], 0, 0, 0);
        s[1][n] = __builtin_amdgcn_mfma_f32_16x16x32_bf16(qf[1][kk], kf, s[1][n], 0, 0, 0);
      }
    }

    // causal mask (diagonal-crossing tiles only)
    const int kb = kt * 64;
    if (kb + 63 > q0 + w*32) {
#pragma unroll
      for (int m = 0; m < 2; ++m)
#pragma unroll
        for (int n = 0; n < 4; ++n)
#pragma unroll
          for (int j = 0; j < 4; ++j) {
            const int keyg = kb + n*16 + lr;
            const int qg   = q0 + w*32 + m*16 + grp*4 + j;
            if (keyg > qg) s[m][n][j] = -1e30f;
          }
    }

    // online softmax (per q-row; row spread over 16-lane group)
#pragma unroll
    for (int m = 0; m < 2; ++m) {
#pragma unroll
      for (int j = 0; j < 4; ++j) {
        float mt = fmaxf(fmaxf(s[m][0][j], s[m][1][j]), fmaxf(s[m][2][j], s[m][3][j]));
        mt = fmaxf(mt, __shfl_xor(mt, 1));
        mt = fmaxf(mt, __shfl_xor(mt, 2));
        mt = fmaxf(mt, __shfl_xor(mt, 4));
        mt = fmaxf(mt, __shfl_xor(mt, 8));
        const float mn = fmaxf(mrow[m][j], mt);
        const float alpha = exp2f(mrow[m][j] - mn);
        mrow[m][j] = mn;
        float ps = 0.f;
#pragma unroll
        for (int n = 0; n < 4; ++n) {
          const float p = exp2f(s[m][n][j] - mn);
          s[m][n][j] = p;
          ps += p;
        }
        ps += __shfl_xor(ps, 1);
        ps += __shfl_xor(ps, 2);
        ps += __shfl_xor(ps, 4);
        ps += __shfl_xor(ps, 8);
        lrow[m][j] = lrow[m][j] * alpha + ps;
#pragma unroll
        for (int dn = 0; dn < 4; ++dn) accO[m][dn][j] *= alpha;
      }
    }

    // P -> LDS (bf16), wave-private region; same-wave dependence only
#pragma unroll
    for (int m = 0; m < 2; ++m)
#pragma unroll
      for (int n = 0; n < 4; ++n)
#pragma unroll
        for (int j = 0; j < 4; ++j)
          lP[w][(m*16 + grp*4 + j)*72 + n*16 + lr] = f2bf(s[m][n][j]);

    // PV
    short8 pa[2][2];
#pragma unroll
    for (int m = 0; m < 2; ++m)
#pragma unroll
      for (int kk = 0; kk < 2; ++kk)
        pa[m][kk] = *(const short8*)&lP[w][(m*16 + lr)*72 + kk*32 + grp*8];
#pragma unroll
    for (int dn = 0; dn < 4; ++dn) {
      const int d = dn*16 + lr;
#pragma unroll
      for (int kk = 0; kk < 2; ++kk) {
        const int gp = (kk*4 + grp) ^ (d & 7);
        short8 vf = *(const short8*)&lV[cur][d*64 + gp*8];
        accO[0][dn] = __builtin_amdgcn_mfma_f32_16x16x32_bf16(pa[0][kk], vf, accO[0][dn], 0, 0, 0);
        accO[1][dn] = __builtin_amdgcn_mfma_f32_16x16x32_bf16(pa[1][kk], vf, accO[1][dn], 0, 0, 0);
      }
    }
    __syncthreads();
  }
#undef STAGEKV

  // epilogue: O[token][h*64+d] bf16
  const int b = bh >> 4, h = bh & 15;
#pragma unroll
  for (int m = 0; m < 2; ++m)
#pragma unroll
    for (int dn = 0; dn < 4; ++dn)
#pragma unroll
      for (int j = 0; j < 4; ++j) {
        const int qg = q0 + w*32 + m*16 + grp*4 + j;
        const int token = b*2048 + qg;
        const int col = h*64 + dn*16 + lr;
        O[token*1024 + col] = f2bf(accO[m][dn][j] / lrow[m][j]);
      }
}

// ---------------- launcher ----------------
extern "C" void kernel_launch(void* const* d_in, const int* in_sizes, int n_in,
                              void* d_out, int out_size, void* d_ws, size_t ws_size,
                              hipStream_t stream) {
  const float* x  = (const float*)d_in[0];
  const float* Wq = (const float*)d_in[1];
  const float* bq = (const float*)d_in[2];
  const float* Wk = (const float*)d_in[3];
  const float* bk = (const float*)d_in[4];
  const float* Wv = (const float*)d_in[5];
  const float* bv = (const float*)d_in[6];
  const float* Wo = (const float*)d_in[7];
  const float* bo = (const float*)d_in[8];
  float* out = (float*)d_out;

  char* ws = (char*)d_ws;
  u16* xb  = (u16*)(ws + 0);          // [4096][1024] bf16
  u16* wqb = (u16*)(ws + 8388608);
  u16* wkb = (u16*)(ws + 10485760);
  u16* wvb = (u16*)(ws + 12582912);
  u16* wob = (u16*)(ws + 14680064);
  u16* Qb  = (u16*)(ws + 16777216);   // [32][2048][64]
  u16* Kb  = (u16*)(ws + 25165824);   // [32][2048][64]
  u16* Vb  = (u16*)(ws + 33554432);   // [32][64][2048]
  u16* Ab  = (u16*)(ws + 41943040);   // [4096][1024]

  k_cvt<<<dim3(4096), 256, 0, stream>>>(x,  xb,  1048576);
  k_cvt<<<dim3(1024), 256, 0, stream>>>(Wq, wqb, 262144);
  k_cvt<<<dim3(1024), 256, 0, stream>>>(Wk, wkb, 262144);
  k_cvt<<<dim3(1024), 256, 0, stream>>>(Wv, wvb, 262144);
  k_cvt<<<dim3(1024), 256, 0, stream>>>(Wo, wob, 262144);

  k_gemm<<<dim3(8, 32, 3), 256, 0, stream>>>(xb, wqb, wkb, wvb, bq, bk, bv,
                                             Qb, Kb, Vb, nullptr, 0);

  k_attn<<<dim3(16, 32), 256, 0, stream>>>(Qb, Kb, Vb, Ab);

  k_gemm<<<dim3(8, 32, 1), 256, 0, stream>>>(Ab, wob, wob, wob, bo, bo, bo,
                                             nullptr, nullptr, nullptr, out, 1);
}

// Round 2
// 175.683 us; speedup vs baseline: 1.3208x; 1.3208x over previous
//
#include <hip/hip_runtime.h>

typedef unsigned short u16;
typedef __attribute__((ext_vector_type(8))) short short8;
typedef __attribute__((ext_vector_type(4))) float floatx4;

__device__ __forceinline__ u16 f2bf(float x){
  union { float f; unsigned u; } v; v.f = x;
  unsigned r = v.u + 0x7fffu + ((v.u >> 16) & 1u);
  return (u16)(r >> 16);
}

__device__ __forceinline__ unsigned cvt_pk_bf16(float lo, float hi){
  unsigned r;
  asm("v_cvt_pk_bf16_f32 %0, %1, %2" : "=v"(r) : "v"(lo), "v"(hi));
  return r;
}

__device__ __forceinline__ void gld16(const u16* g, u16* l){
  __builtin_amdgcn_global_load_lds(
      (const __attribute__((address_space(1))) void*)g,
      (__attribute__((address_space(3))) void*)l, 16, 0, 0);
}

// ---------------- fused fp32 -> bf16 convert (x + 4 weights, one launch) -------
__global__ void k_cvt_all(const float* __restrict__ x,
                          const float* __restrict__ wq, const float* __restrict__ wk,
                          const float* __restrict__ wv, const float* __restrict__ wo,
                          u16* __restrict__ xb, u16* __restrict__ wqb, u16* __restrict__ wkb,
                          u16* __restrict__ wvb, u16* __restrict__ wob){
  const int i = blockIdx.x * 256 + threadIdx.x;   // float4 index, total 2097152
  const float* s; u16* d; int off;
  if (i < 1048576) { s = x; d = xb; off = i; }
  else {
    const int j = i - 1048576;
    const int wsel = j >> 18;          // 262144 f4 per weight
    off = j & 262143;
    s = (wsel==0) ? wq : (wsel==1) ? wk : (wsel==2) ? wv : wo;
    d = (wsel==0) ? wqb : (wsel==1) ? wkb : (wsel==2) ? wvb : wob;
  }
  const float4 f = ((const float4*)s)[off];
  unsigned lo = (unsigned)f2bf(f.x) | ((unsigned)f2bf(f.y) << 16);
  unsigned hi = (unsigned)f2bf(f.z) | ((unsigned)f2bf(f.w) << 16);
  ((uint2*)d)[off] = make_uint2(lo, hi);
}

// ---------------- GEMM: C[4096][1024] = A[4096][1024] * W[1024][1024]^T + b --------
// mode 0: Q (bf16 out, [bh][s][64], *qscale)   mode 1: K (bf16, [bh][s][64])
// mode 2: V (bf16, [bh][64][s])                mode 3: fp32 out [4096][1024]
__global__ __launch_bounds__(256) void k_gemm(
    const u16* __restrict__ A,
    const u16* __restrict__ Wq, const u16* __restrict__ Wk, const u16* __restrict__ Wv,
    const float* __restrict__ bq, const float* __restrict__ bk, const float* __restrict__ bv,
    u16* __restrict__ Qo, u16* __restrict__ Ko, u16* __restrict__ Vo,
    float* __restrict__ Fo, int oproj)
{
  const int mode = oproj ? 3 : (int)blockIdx.z;
  const u16* W      = (mode==1) ? Wk : (mode==2) ? Wv : Wq;
  const float* bias = (mode==1) ? bk : (mode==2) ? bv : bq;

  __shared__ u16 lA[2][4096];   // [128 rows][32 k] bf16, k-groups-of-8 swizzled
  __shared__ u16 lB[2][4096];

  const int tid  = threadIdx.x;
  const int row0 = blockIdx.y * 128;
  const int col0 = blockIdx.x * 128;

  const int srow = tid >> 2;                    // 0..63
  const int sgp  = tid & 3;
  const int sgl  = sgp ^ ((srow >> 1) & 3);
  const u16* ga0 = A + (row0 + srow)      * 1024 + sgl * 8;
  const u16* ga1 = A + (row0 + srow + 64) * 1024 + sgl * 8;
  const u16* gb0 = W + (col0 + srow)      * 1024 + sgl * 8;
  const u16* gb1 = W + (col0 + srow + 64) * 1024 + sgl * 8;

  const int l  = tid & 63, w = tid >> 6;
  const int wr = w >> 1,  wc = w & 1;
  const int lr = l & 15,  grp = l >> 4;
  const int sw = (lr >> 1) & 3;
  int aoff[4], boff[4];
#pragma unroll
  for (int m = 0; m < 4; ++m) aoff[m] = (wr*64 + m*16 + lr)*32 + ((grp ^ sw) * 8);
#pragma unroll
  for (int n = 0; n < 4; ++n) boff[n] = (wc*64 + n*16 + lr)*32 + ((grp ^ sw) * 8);

  floatx4 acc[4][4];
#pragma unroll
  for (int m = 0; m < 4; ++m)
#pragma unroll
    for (int n = 0; n < 4; ++n) acc[m][n] = (floatx4){0.f, 0.f, 0.f, 0.f};

#define STAGE(buf, kt_) do { \
    const int k0_ = (kt_) * 32; \
    gld16(ga0 + k0_, &lA[(buf)][tid*8]); \
    gld16(ga1 + k0_, &lA[(buf)][2048 + tid*8]); \
    gld16(gb0 + k0_, &lB[(buf)][tid*8]); \
    gld16(gb1 + k0_, &lB[(buf)][2048 + tid*8]); \
  } while (0)

  STAGE(0, 0);
  __syncthreads();
  for (int kt = 0; kt < 32; ++kt) {
    const int cur = kt & 1;
    if (kt < 31) STAGE(cur ^ 1, kt + 1);
    short8 af[4], bf[4];
#pragma unroll
    for (int m = 0; m < 4; ++m) af[m] = *(const short8*)&lA[cur][aoff[m]];
#pragma unroll
    for (int n = 0; n < 4; ++n) bf[n] = *(const short8*)&lB[cur][boff[n]];
#pragma unroll
    for (int m = 0; m < 4; ++m)
#pragma unroll
      for (int n = 0; n < 4; ++n)
        acc[m][n] = __builtin_amdgcn_mfma_f32_16x16x32_bf16(af[m], bf[n], acc[m][n], 0, 0, 0);
    __syncthreads();
  }
#undef STAGE

  if (mode == 3) {
#pragma unroll
    for (int n = 0; n < 4; ++n) {
      const int cg = col0 + wc*64 + n*16 + lr;
      const float bb = bias[cg];
#pragma unroll
      for (int m = 0; m < 4; ++m) {
        const int rg = row0 + wr*64 + m*16 + grp*4;
#pragma unroll
        for (int j = 0; j < 4; ++j)
          Fo[(rg + j) * 1024 + cg] = acc[m][n][j] + bb;
      }
    }
  } else {
    const float sc = (mode == 0) ? 0.18033688011112042f : 1.0f;  // 0.125*log2(e) for Q
    u16* dst = (mode == 0) ? Qo : (mode == 1) ? Ko : Vo;
#pragma unroll
    for (int n = 0; n < 4; ++n) {
      const int cg = col0 + wc*64 + n*16 + lr;
      const float bb = bias[cg];
      const int h = cg >> 6, d = cg & 63;
#pragma unroll
      for (int m = 0; m < 4; ++m) {
#pragma unroll
        for (int j = 0; j < 4; ++j) {
          const int rg = row0 + wr*64 + m*16 + grp*4 + j;
          const int b = rg >> 11, s5 = rg & 2047;
          const float val = (acc[m][n][j] + bb) * sc;
          int idx;
          if (mode == 2) idx = ((b*16 + h)*64 + d)*2048 + s5;
          else           idx = ((b*16 + h)*2048 + s5)*64 + d;
          dst[idx] = f2bf(val);
        }
      }
    }
  }
}

// ---------------- flash attention v2: swapped QK^T, lane-local softmax ----------
// grid: x = qtile (16, reversed so longest first), y = bh (32). 256 thr, 4 waves x 32 q.
// S^T = mfma(K, Q): row=key, col=query(=lane&15). Softmax state is per-lane scalar.
__global__ __launch_bounds__(256, 3) void k_attn(
    const u16* __restrict__ Q, const u16* __restrict__ K,
    const u16* __restrict__ V, u16* __restrict__ O)
{
  __shared__ u16 lK[2][4096];     // [64 keys][64 dk] groups-of-8 swizzled
  __shared__ u16 lV[2][4096];     // [64 dk][64 keys] (V^T) swizzled
  __shared__ u16 lP[4][2048];     // [wave][32 q][64 keys] group-swizzled

  const int tid = threadIdx.x;
  const int qt = 15 - (int)blockIdx.x;     // longest blocks dispatch first
  const int bh = blockIdx.y;
  const int l = tid & 63, w = tid >> 6;
  const int lr = l & 15, grp = l >> 4;
  const int q0 = qt * 128;
  const int qw0 = q0 + w * 32;

  const u16* Qh = Q + (size_t)bh * 2048 * 64;
  const u16* Kh = K + (size_t)bh * 2048 * 64;
  const u16* Vh = V + (size_t)bh * 64 * 2048;

  // Q fragments (B-operand: lane holds Q[qw0+m*16+lr][kk*32+grp*8..+7])
  short8 qf[2][2];
#pragma unroll
  for (int m = 0; m < 2; ++m)
#pragma unroll
    for (int kk = 0; kk < 2; ++kk)
      qf[m][kk] = *(const short8*)(Qh + (qw0 + m*16 + lr)*64 + kk*32 + grp*8);

  floatx4 accO[2][4];              // O^T: [d=dn*16+grp*4+j][q=lr]
  float mrow[2], lrow[2];
#pragma unroll
  for (int m = 0; m < 2; ++m) {
    mrow[m] = -1e30f; lrow[m] = 0.f;
#pragma unroll
    for (int dn = 0; dn < 4; ++dn) accO[m][dn] = (floatx4){0.f, 0.f, 0.f, 0.f};
  }

  const int srow = tid >> 3, sgp = tid & 7;
  const int sgl = sgp ^ (srow & 7);
  const int nkt = 2*qt + 2;
  u16* lPw = &lP[w][0];
  const int swz = lr & 7;

#define STAGEKV(buf, kt_) do { \
    gld16(Kh + ((kt_)*64 + srow     )*64 + sgl*8, &lK[(buf)][tid*8]); \
    gld16(Kh + ((kt_)*64 + srow + 32)*64 + sgl*8, &lK[(buf)][2048 + tid*8]); \
    gld16(Vh + (srow     )*2048 + (kt_)*64 + sgl*8, &lV[(buf)][tid*8]); \
    gld16(Vh + (srow + 32)*2048 + (kt_)*64 + sgl*8, &lV[(buf)][2048 + tid*8]); \
  } while (0)

  STAGEKV(0, 0);
  __syncthreads();

  for (int kt = 0; kt < nkt; ++kt) {
    const int cur = kt & 1;
    if (kt + 1 < nkt) STAGEKV(cur ^ 1, kt + 1);
    const int kb = kt * 64;

    if (kb <= qw0 + 31) {          // wave has at least one unmasked (q,key) pair
      // S^T = K Q^T : st[m][n] reg j -> key = kb+n*16+grp*4+j, query = qw0+m*16+lr
      floatx4 st[2][4];
#pragma unroll
      for (int m = 0; m < 2; ++m)
#pragma unroll
        for (int n = 0; n < 4; ++n) st[m][n] = (floatx4){0.f, 0.f, 0.f, 0.f};
#pragma unroll
      for (int n = 0; n < 4; ++n) {
        const int key = n*16 + lr;
#pragma unroll
        for (int kk = 0; kk < 2; ++kk) {
          const int gp = (kk*4 + grp) ^ (key & 7);
          short8 kf = *(const short8*)&lK[cur][key*64 + gp*8];
          st[0][n] = __builtin_amdgcn_mfma_f32_16x16x32_bf16(kf, qf[0][kk], st[0][n], 0, 0, 0);
          st[1][n] = __builtin_amdgcn_mfma_f32_16x16x32_bf16(kf, qf[1][kk], st[1][n], 0, 0, 0);
        }
      }

      // causal mask
      if (kb + 63 > qw0) {
#pragma unroll
        for (int m = 0; m < 2; ++m) {
          const int myq = qw0 + m*16 + lr;
#pragma unroll
          for (int n = 0; n < 4; ++n)
#pragma unroll
            for (int j = 0; j < 4; ++j)
              if (kb + n*16 + grp*4 + j > myq) st[m][n][j] = -1e30f;
        }
      }

      // online softmax: per-lane scalar state, 2 shuffles per reduce
#pragma unroll
      for (int m = 0; m < 2; ++m) {
        float mt = st[m][0][0];
#pragma unroll
        for (int n = 0; n < 4; ++n)
#pragma unroll
          for (int j = 0; j < 4; ++j) mt = fmaxf(mt, st[m][n][j]);
        mt = fmaxf(mt, __shfl_xor(mt, 16));
        mt = fmaxf(mt, __shfl_xor(mt, 32));
        const float mn = fmaxf(mrow[m], mt);
        const float alpha = exp2f(mrow[m] - mn);
        mrow[m] = mn;
        float ps = 0.f;
#pragma unroll
        for (int n = 0; n < 4; ++n)
#pragma unroll
          for (int j = 0; j < 4; ++j) {
            const float p = exp2f(st[m][n][j] - mn);
            st[m][n][j] = p;
            ps += p;
          }
        ps += __shfl_xor(ps, 16);
        ps += __shfl_xor(ps, 32);
        lrow[m] = lrow[m] * alpha + ps;
#pragma unroll
        for (int dn = 0; dn < 4; ++dn) accO[m][dn] *= alpha;

        // pack P -> LDS [q][key], keys in swizzled groups-of-8; 2-way banks (free)
#pragma unroll
        for (int n = 0; n < 4; ++n)
#pragma unroll
          for (int p2 = 0; p2 < 2; ++p2) {
            const unsigned pk = cvt_pk_bf16(st[m][n][2*p2], st[m][n][2*p2+1]);
            const int pg = (2*n + (grp >> 1)) ^ swz;
            ((unsigned*)lPw)[(m*16 + lr)*32 + pg*4 + (grp & 1)*2 + p2] = pk;
          }
      }

      asm volatile("s_waitcnt lgkmcnt(0)" ::: "memory");

      short8 pa[2][2];
#pragma unroll
      for (int m = 0; m < 2; ++m)
#pragma unroll
        for (int kk = 0; kk < 2; ++kk)
          pa[m][kk] = *(const short8*)&lPw[(m*16 + lr)*64 + (((kk*4 + grp) ^ swz) * 8)];

      // O^T += V^T P : accO[m][dn] reg j -> d = dn*16+grp*4+j, q = qw0+m*16+lr
#pragma unroll
      for (int dn = 0; dn < 4; ++dn) {
        const int d = dn*16 + lr;
#pragma unroll
        for (int kk = 0; kk < 2; ++kk) {
          const int gp = (kk*4 + grp) ^ (d & 7);
          short8 vf = *(const short8*)&lV[cur][d*64 + gp*8];
          accO[0][dn] = __builtin_amdgcn_mfma_f32_16x16x32_bf16(vf, pa[0][kk], accO[0][dn], 0, 0, 0);
          accO[1][dn] = __builtin_amdgcn_mfma_f32_16x16x32_bf16(vf, pa[1][kk], accO[1][dn], 0, 0, 0);
        }
      }
    }
    __syncthreads();
  }
#undef STAGEKV

  // epilogue: O[token][h*64+d] bf16, packed u32 stores
  const int b = bh >> 4, h = bh & 15;
#pragma unroll
  for (int m = 0; m < 2; ++m) {
    const float inv = 1.0f / lrow[m];
    const int token = b*2048 + qw0 + m*16 + lr;
#pragma unroll
    for (int dn = 0; dn < 4; ++dn)
#pragma unroll
      for (int p2 = 0; p2 < 2; ++p2) {
        const unsigned pk = cvt_pk_bf16(accO[m][dn][2*p2] * inv, accO[m][dn][2*p2+1] * inv);
        *(unsigned*)&O[token*1024 + h*64 + dn*16 + grp*4 + 2*p2] = pk;
      }
  }
}

// ---------------- launcher ----------------
extern "C" void kernel_launch(void* const* d_in, const int* in_sizes, int n_in,
                              void* d_out, int out_size, void* d_ws, size_t ws_size,
                              hipStream_t stream) {
  const float* x  = (const float*)d_in[0];
  const float* Wq = (const float*)d_in[1];
  const float* bq = (const float*)d_in[2];
  const float* Wk = (const float*)d_in[3];
  const float* bk = (const float*)d_in[4];
  const float* Wv = (const float*)d_in[5];
  const float* bv = (const float*)d_in[6];
  const float* Wo = (const float*)d_in[7];
  const float* bo = (const float*)d_in[8];
  float* out = (float*)d_out;

  char* ws = (char*)d_ws;
  u16* xb  = (u16*)(ws + 0);          // [4096][1024] bf16
  u16* wqb = (u16*)(ws + 8388608);
  u16* wkb = (u16*)(ws + 10485760);
  u16* wvb = (u16*)(ws + 12582912);
  u16* wob = (u16*)(ws + 14680064);
  u16* Qb  = (u16*)(ws + 16777216);   // [32][2048][64]
  u16* Kb  = (u16*)(ws + 25165824);   // [32][2048][64]
  u16* Vb  = (u16*)(ws + 33554432);   // [32][64][2048]
  u16* Ab  = (u16*)(ws + 41943040);   // [4096][1024]

  k_cvt_all<<<dim3(8192), 256, 0, stream>>>(x, Wq, Wk, Wv, Wo, xb, wqb, wkb, wvb, wob);

  k_gemm<<<dim3(8, 32, 3), 256, 0, stream>>>(xb, wqb, wkb, wvb, bq, bk, bv,
                                             Qb, Kb, Vb, nullptr, 0);

  k_attn<<<dim3(16, 32), 256, 0, stream>>>(Qb, Kb, Vb, Ab);

  k_gemm<<<dim3(8, 32, 1), 256, 0, stream>>>(Ab, wob, wob, wob, bo, bo, bo,
                                             nullptr, nullptr, nullptr, out, 1);
}

// Round 3
// 171.003 us; speedup vs baseline: 1.3570x; 1.0274x over previous
//
#include <hip/hip_runtime.h>

typedef unsigned short u16;
typedef __attribute__((ext_vector_type(8))) short short8;
typedef __attribute__((ext_vector_type(4))) float floatx4;

__device__ __forceinline__ u16 f2bf(float x){
  union { float f; unsigned u; } v; v.f = x;
  unsigned r = v.u + 0x7fffu + ((v.u >> 16) & 1u);
  return (u16)(r >> 16);
}

__device__ __forceinline__ unsigned cvt_pk_bf16(float lo, float hi){
  unsigned r;
  asm("v_cvt_pk_bf16_f32 %0, %1, %2" : "=v"(r) : "v"(lo), "v"(hi));
  return r;
}

__device__ __forceinline__ void gld16(const u16* g, u16* l){
  __builtin_amdgcn_global_load_lds(
      (const __attribute__((address_space(1))) void*)g,
      (__attribute__((address_space(3))) void*)l, 16, 0, 0);
}

// ---------------- fused fp32 -> bf16 convert (x + 4 weights, one launch) -------
__global__ void k_cvt_all(const float* __restrict__ x,
                          const float* __restrict__ wq, const float* __restrict__ wk,
                          const float* __restrict__ wv, const float* __restrict__ wo,
                          u16* __restrict__ xb, u16* __restrict__ wqb, u16* __restrict__ wkb,
                          u16* __restrict__ wvb, u16* __restrict__ wob){
  const int i = blockIdx.x * 256 + threadIdx.x;   // float4 index, total 2097152
  const float* s; u16* d; int off;
  if (i < 1048576) { s = x; d = xb; off = i; }
  else {
    const int j = i - 1048576;
    const int wsel = j >> 18;          // 262144 f4 per weight
    off = j & 262143;
    s = (wsel==0) ? wq : (wsel==1) ? wk : (wsel==2) ? wv : wo;
    d = (wsel==0) ? wqb : (wsel==1) ? wkb : (wsel==2) ? wvb : wob;
  }
  const float4 f = ((const float4*)s)[off];
  unsigned lo = (unsigned)f2bf(f.x) | ((unsigned)f2bf(f.y) << 16);
  unsigned hi = (unsigned)f2bf(f.z) | ((unsigned)f2bf(f.w) << 16);
  ((uint2*)d)[off] = make_uint2(lo, hi);
}

// ---------------- GEMM: C[4096][1024] = A[4096][1024] * W[1024][1024]^T + b --------
// mode 0: Q (bf16 out, [bh][s][64], *qscale)   mode 1: K (bf16, [bh][s][64])
// mode 2: V (bf16, [bh][64][s])                mode 3: fp32 out [4096][1024]
__global__ __launch_bounds__(256) void k_gemm(
    const u16* __restrict__ A,
    const u16* __restrict__ Wq, const u16* __restrict__ Wk, const u16* __restrict__ Wv,
    const float* __restrict__ bq, const float* __restrict__ bk, const float* __restrict__ bv,
    u16* __restrict__ Qo, u16* __restrict__ Ko, u16* __restrict__ Vo,
    float* __restrict__ Fo, int oproj)
{
  const int mode = oproj ? 3 : (int)blockIdx.z;
  const u16* W      = (mode==1) ? Wk : (mode==2) ? Wv : Wq;
  const float* bias = (mode==1) ? bk : (mode==2) ? bv : bq;

  __shared__ u16 lA[2][4096];   // [128 rows][32 k] bf16, k-groups-of-8 swizzled
  __shared__ u16 lB[2][4096];

  const int tid  = threadIdx.x;
  const int row0 = blockIdx.y * 128;
  const int col0 = blockIdx.x * 128;

  const int srow = tid >> 2;                    // 0..63
  const int sgp  = tid & 3;
  const int sgl  = sgp ^ ((srow >> 1) & 3);
  const u16* ga0 = A + (row0 + srow)      * 1024 + sgl * 8;
  const u16* ga1 = A + (row0 + srow + 64) * 1024 + sgl * 8;
  const u16* gb0 = W + (col0 + srow)      * 1024 + sgl * 8;
  const u16* gb1 = W + (col0 + srow + 64) * 1024 + sgl * 8;

  const int l  = tid & 63, w = tid >> 6;
  const int wr = w >> 1,  wc = w & 1;
  const int lr = l & 15,  grp = l >> 4;
  const int sw = (lr >> 1) & 3;
  int aoff[4], boff[4];
#pragma unroll
  for (int m = 0; m < 4; ++m) aoff[m] = (wr*64 + m*16 + lr)*32 + ((grp ^ sw) * 8);
#pragma unroll
  for (int n = 0; n < 4; ++n) boff[n] = (wc*64 + n*16 + lr)*32 + ((grp ^ sw) * 8);

  floatx4 acc[4][4];
#pragma unroll
  for (int m = 0; m < 4; ++m)
#pragma unroll
    for (int n = 0; n < 4; ++n) acc[m][n] = (floatx4){0.f, 0.f, 0.f, 0.f};

#define STAGE(buf, kt_) do { \
    const int k0_ = (kt_) * 32; \
    gld16(ga0 + k0_, &lA[(buf)][tid*8]); \
    gld16(ga1 + k0_, &lA[(buf)][2048 + tid*8]); \
    gld16(gb0 + k0_, &lB[(buf)][tid*8]); \
    gld16(gb1 + k0_, &lB[(buf)][2048 + tid*8]); \
  } while (0)

  STAGE(0, 0);
  __syncthreads();
  for (int kt = 0; kt < 32; ++kt) {
    const int cur = kt & 1;
    if (kt < 31) STAGE(cur ^ 1, kt + 1);
    short8 af[4], bf[4];
#pragma unroll
    for (int m = 0; m < 4; ++m) af[m] = *(const short8*)&lA[cur][aoff[m]];
#pragma unroll
    for (int n = 0; n < 4; ++n) bf[n] = *(const short8*)&lB[cur][boff[n]];
#pragma unroll
    for (int m = 0; m < 4; ++m)
#pragma unroll
      for (int n = 0; n < 4; ++n)
        acc[m][n] = __builtin_amdgcn_mfma_f32_16x16x32_bf16(af[m], bf[n], acc[m][n], 0, 0, 0);
    __syncthreads();
  }
#undef STAGE

  if (mode == 3) {
#pragma unroll
    for (int n = 0; n < 4; ++n) {
      const int cg = col0 + wc*64 + n*16 + lr;
      const float bb = bias[cg];
#pragma unroll
      for (int m = 0; m < 4; ++m) {
        const int rg = row0 + wr*64 + m*16 + grp*4;
#pragma unroll
        for (int j = 0; j < 4; ++j)
          Fo[(rg + j) * 1024 + cg] = acc[m][n][j] + bb;
      }
    }
  } else {
    const float sc = (mode == 0) ? 0.18033688011112042f : 1.0f;  // 0.125*log2(e) for Q
    u16* dst = (mode == 0) ? Qo : (mode == 1) ? Ko : Vo;
#pragma unroll
    for (int n = 0; n < 4; ++n) {
      const int cg = col0 + wc*64 + n*16 + lr;
      const float bb = bias[cg];
      const int h = cg >> 6, d = cg & 63;
#pragma unroll
      for (int m = 0; m < 4; ++m) {
#pragma unroll
        for (int j = 0; j < 4; ++j) {
          const int rg = row0 + wr*64 + m*16 + grp*4 + j;
          const int b = rg >> 11, s5 = rg & 2047;
          const float val = (acc[m][n][j] + bb) * sc;
          int idx;
          if (mode == 2) idx = ((b*16 + h)*64 + d)*2048 + s5;
          else           idx = ((b*16 + h)*2048 + s5)*64 + d;
          dst[idx] = f2bf(val);
        }
      }
    }
  }
}

// ---------------- flash attention v3: QBLK=64, 4 blocks/CU, XCD-chunked ----------
// grid: 32x32 = 1024 blocks. 256 thr = 4 waves x 16 q-rows. KVBLK=64.
// S^T = mfma(K, Q): row=key, col=query(=lane&15). Softmax state per-lane scalar.
__global__ __launch_bounds__(256, 4) void k_attn(
    const u16* __restrict__ Q, const u16* __restrict__ K,
    const u16* __restrict__ V, u16* __restrict__ O)
{
  __shared__ u16 lK[2][4096];     // [64 keys][64 dk] groups-of-8 swizzled
  __shared__ u16 lV[2][4096];     // [64 dk][64 keys] (V^T) swizzled
  __shared__ u16 lP[4][1024];     // [wave][16 q][64 keys] group-swizzled

  const int tid = threadIdx.x;
  // XCD-chunked bijective swizzle: 1024 blocks, 128 per XCD -> 4 bh per XCD (L2-resident K/V)
  const int bid = (int)blockIdx.x + 32 * (int)blockIdx.y;
  const int lid = (bid & 7) * 128 + (bid >> 3);
  const int qt = 31 - (lid & 31);          // longest blocks first within chunk
  const int bh = lid >> 5;

  const int l = tid & 63, w = tid >> 6;
  const int lr = l & 15, grp = l >> 4;
  const int q0 = qt * 64;
  const int qw0 = q0 + w * 16;

  const u16* Qh = Q + (size_t)bh * 2048 * 64;
  const u16* Kh = K + (size_t)bh * 2048 * 64;
  const u16* Vh = V + (size_t)bh * 64 * 2048;

  // Q fragments (B-operand: lane holds Q[qw0+lr][kk*32+grp*8..+7])
  short8 qf[2];
#pragma unroll
  for (int kk = 0; kk < 2; ++kk)
    qf[kk] = *(const short8*)(Qh + (qw0 + lr)*64 + kk*32 + grp*8);

  floatx4 accO[4];                 // O^T: [d=dn*16+grp*4+j][q=lr]
  float mrow = -1e30f, lrow = 0.f;
#pragma unroll
  for (int dn = 0; dn < 4; ++dn) accO[dn] = (floatx4){0.f, 0.f, 0.f, 0.f};

  const int srow = tid >> 3, sgp = tid & 7;
  const int sgl = sgp ^ (srow & 7);
  const int nkt = qt + 1;
  u16* lPw = &lP[w][0];
  const int swz = lr & 7;

#define STAGEKV(buf, kt_) do { \
    gld16(Kh + ((kt_)*64 + srow     )*64 + sgl*8, &lK[(buf)][tid*8]); \
    gld16(Kh + ((kt_)*64 + srow + 32)*64 + sgl*8, &lK[(buf)][2048 + tid*8]); \
    gld16(Vh + (srow     )*2048 + (kt_)*64 + sgl*8, &lV[(buf)][tid*8]); \
    gld16(Vh + (srow + 32)*2048 + (kt_)*64 + sgl*8, &lV[(buf)][2048 + tid*8]); \
  } while (0)

  STAGEKV(0, 0);
  __syncthreads();

  for (int kt = 0; kt < nkt; ++kt) {
    const int cur = kt & 1;
    if (kt + 1 < nkt) STAGEKV(cur ^ 1, kt + 1);
    const int kb = kt * 64;

    if (kb <= qw0 + 15) {          // wave has at least one unmasked (q,key) pair
      // S^T = K Q^T : st[n] reg j -> key = kb+n*16+grp*4+j, query = qw0+lr
      floatx4 st[4];
#pragma unroll
      for (int n = 0; n < 4; ++n) st[n] = (floatx4){0.f, 0.f, 0.f, 0.f};
#pragma unroll
      for (int n = 0; n < 4; ++n) {
        const int key = n*16 + lr;
#pragma unroll
        for (int kk = 0; kk < 2; ++kk) {
          const int gp = (kk*4 + grp) ^ (key & 7);
          short8 kf = *(const short8*)&lK[cur][key*64 + gp*8];
          st[n] = __builtin_amdgcn_mfma_f32_16x16x32_bf16(kf, qf[kk], st[n], 0, 0, 0);
        }
      }

      // causal mask (diagonal tile only reaches here with partial coverage)
      const int lim = qw0 + lr - kb;     // key offset <= lim is valid
      if (63 > lim) {
#pragma unroll
        for (int n = 0; n < 4; ++n)
#pragma unroll
          for (int j = 0; j < 4; ++j)
            if (n*16 + grp*4 + j > lim) st[n][j] = -1e30f;
      }

      // online softmax: per-lane scalar state, 2 shuffles per reduce
      float mt = st[0][0];
#pragma unroll
      for (int n = 0; n < 4; ++n)
#pragma unroll
        for (int j = 0; j < 4; ++j) mt = fmaxf(mt, st[n][j]);
      mt = fmaxf(mt, __shfl_xor(mt, 16));
      mt = fmaxf(mt, __shfl_xor(mt, 32));
      const float mn = fmaxf(mrow, mt);
      const float alpha = exp2f(mrow - mn);
      mrow = mn;
      float ps = 0.f;
#pragma unroll
      for (int n = 0; n < 4; ++n)
#pragma unroll
        for (int j = 0; j < 4; ++j) {
          const float p = exp2f(st[n][j] - mn);
          st[n][j] = p;
          ps += p;
        }
      ps += __shfl_xor(ps, 16);
      ps += __shfl_xor(ps, 32);
      lrow = lrow * alpha + ps;
#pragma unroll
      for (int dn = 0; dn < 4; ++dn) accO[dn] *= alpha;

      // pack P -> LDS [q][key], keys in swizzled groups-of-8; 2-way banks (free)
#pragma unroll
      for (int n = 0; n < 4; ++n)
#pragma unroll
        for (int p2 = 0; p2 < 2; ++p2) {
          const unsigned pk = cvt_pk_bf16(st[n][2*p2], st[n][2*p2+1]);
          const int pg = (2*n + (grp >> 1)) ^ swz;
          ((unsigned*)lPw)[lr*32 + pg*4 + (grp & 1)*2 + p2] = pk;
        }

      asm volatile("s_waitcnt lgkmcnt(0)" ::: "memory");

      short8 pa[2];
#pragma unroll
      for (int kk = 0; kk < 2; ++kk)
        pa[kk] = *(const short8*)&lPw[lr*64 + (((kk*4 + grp) ^ swz) * 8)];

      // O^T += V^T P : accO[dn] reg j -> d = dn*16+grp*4+j, q = qw0+lr
#pragma unroll
      for (int dn = 0; dn < 4; ++dn) {
        const int d = dn*16 + lr;
#pragma unroll
        for (int kk = 0; kk < 2; ++kk) {
          const int gp = (kk*4 + grp) ^ (d & 7);
          short8 vf = *(const short8*)&lV[cur][d*64 + gp*8];
          accO[dn] = __builtin_amdgcn_mfma_f32_16x16x32_bf16(vf, pa[kk], accO[dn], 0, 0, 0);
        }
      }
    }
    __syncthreads();
  }
#undef STAGEKV

  // epilogue: O[token][h*64+d] bf16, packed u32 stores
  const int b = bh >> 4, h = bh & 15;
  const float inv = 1.0f / lrow;
  const int token = b*2048 + qw0 + lr;
#pragma unroll
  for (int dn = 0; dn < 4; ++dn)
#pragma unroll
    for (int p2 = 0; p2 < 2; ++p2) {
      const unsigned pk = cvt_pk_bf16(accO[dn][2*p2] * inv, accO[dn][2*p2+1] * inv);
      *(unsigned*)&O[token*1024 + h*64 + dn*16 + grp*4 + 2*p2] = pk;
    }
}

// ---------------- launcher ----------------
extern "C" void kernel_launch(void* const* d_in, const int* in_sizes, int n_in,
                              void* d_out, int out_size, void* d_ws, size_t ws_size,
                              hipStream_t stream) {
  const float* x  = (const float*)d_in[0];
  const float* Wq = (const float*)d_in[1];
  const float* bq = (const float*)d_in[2];
  const float* Wk = (const float*)d_in[3];
  const float* bk = (const float*)d_in[4];
  const float* Wv = (const float*)d_in[5];
  const float* bv = (const float*)d_in[6];
  const float* Wo = (const float*)d_in[7];
  const float* bo = (const float*)d_in[8];
  float* out = (float*)d_out;

  char* ws = (char*)d_ws;
  u16* xb  = (u16*)(ws + 0);          // [4096][1024] bf16
  u16* wqb = (u16*)(ws + 8388608);
  u16* wkb = (u16*)(ws + 10485760);
  u16* wvb = (u16*)(ws + 12582912);
  u16* wob = (u16*)(ws + 14680064);
  u16* Qb  = (u16*)(ws + 16777216);   // [32][2048][64]
  u16* Kb  = (u16*)(ws + 25165824);   // [32][2048][64]
  u16* Vb  = (u16*)(ws + 33554432);   // [32][64][2048]
  u16* Ab  = (u16*)(ws + 41943040);   // [4096][1024]

  k_cvt_all<<<dim3(8192), 256, 0, stream>>>(x, Wq, Wk, Wv, Wo, xb, wqb, wkb, wvb, wob);

  k_gemm<<<dim3(8, 32, 3), 256, 0, stream>>>(xb, wqb, wkb, wvb, bq, bk, bv,
                                             Qb, Kb, Vb, nullptr, 0);

  k_attn<<<dim3(32, 32), 256, 0, stream>>>(Qb, Kb, Vb, Ab);

  k_gemm<<<dim3(8, 32, 1), 256, 0, stream>>>(Ab, wob, wob, wob, bo, bo, bo,
                                             nullptr, nullptr, nullptr, out, 1);
}